// Round 8
// baseline (19.833 us; speedup 1.0000x reference)
//
#include <hip/hip_runtime.h>

#define POOL 7
#define SCALE 0.0625f
#define HW 10000      // 100*100 plane elements
#define NROI 512
#define NCH 245
#define JJ 64         // c-stride between a block's planes

typedef const __attribute__((address_space(1))) void* gas_ptr;
typedef __attribute__((address_space(3))) void* las_ptr;

// 512 blocks (2/CU), each processes 3-4 channel planes of one batch with a
// double-buffered LDS pipeline:
//   stage(next plane) -> s_waitcnt vmcnt(5) (counted: next stays in flight)
//   -> s_barrier -> gather+bilinear+store -> s_barrier
// so the HBM/L3->LDS DMA streams continuously instead of the old
// stage-all / drain / compute-all convoy (4 co-resident blocks in lockstep).
// bid&7 = b keeps the XCD write-merge from round 7 (all stores of batch b
// land in XCD b's L2; lines written back once, fully populated).
// Every wave issues exactly 5 global_load_lds per stage -> vmcnt(5) == "the
// previous plane's 5 DMAs retired" (in-order retirement).
__global__ __launch_bounds__(512) void psroi_kernel(
    const float* __restrict__ x, const float* __restrict__ boxes,
    float* __restrict__ out)
{
    __shared__ float plane[2][HW + 4];

    const int H = 100, W = 100;
    int bid = blockIdx.x;
    int b = bid & 7;             // batch == target XCD
    int j = bid >> 3;            // 0..63, plane set: c = j + 64*t
    int npl = (j < 53) ? 4 : 3;  // c<=244

    int n = threadIdx.x;              // roi within batch
    int r = b * NROI + n;             // global roi id
    int lane = threadIdx.x & 63;
    int wave = threadIdx.x >> 6;

    const float* xb = x + (size_t)b * NCH * HW;

    auto stage = [&](int buf, int c) {
        const float4* src4 = (const float4*)(xb + (size_t)c * HW);
        #pragma unroll
        for (int i = 0; i < 5; ++i) {
            int chunk_base = i * 512 + wave * 64;   // float4 units
            int chunk = chunk_base + lane;
            if (chunk < HW / 4) {
                __builtin_amdgcn_global_load_lds(
                    (gas_ptr)(src4 + chunk),
                    (las_ptr)((char*)&plane[buf][0] + (size_t)chunk_base * 16),
                    16, 0, 0);
            }
        }
    };

    // ---- prologue: boxes, stage plane 0, zero pads ----
    float4 bx = *(const float4*)(boxes + (size_t)r * 4);
    stage(0, j);
    if (threadIdx.x < 8)
        plane[threadIdx.x >> 2][HW + (threadIdx.x & 3)] = 0.f;

    // box-level geometry (plane-independent)
    float sw = bx.x * SCALE - 0.5f;
    float sh = bx.y * SCALE - 0.5f;
    float bin_h = (bx.w * SCALE - 0.5f - sh) / (float)POOL;
    float bin_w = (bx.z * SCALE - 0.5f - sw) / (float)POOL;

    __syncthreads();   // drains prologue vmcnt/lgkmcnt; outstanding = 0

    for (int t = 0; t < npl; ++t) {
        int c = j + JJ * t;
        bool pre = (t + 1 < npl);
        if (pre) stage((t + 1) & 1, j + JJ * (t + 1));

        // per-plane geometry (VALU only; overlaps the DMA wait)
        int ph = (c / POOL) % POOL;
        int pw = c % POOL;
        float fy0 = sh + (float)ph * bin_h;
        float fx0 = sw + (float)pw * bin_w;

        int   rowa[2], rstep[2];
        float wyh[2], wyl[2];
        #pragma unroll
        for (int iy = 0; iy < 2; ++iy) {
            float y  = fy0 + ((float)iy + 0.5f) * bin_h * 0.5f;
            float vy = (y >= -1.0f && y <= (float)H) ? 1.0f : 0.0f;
            float yc = fminf(fmaxf(y, 0.0f), (float)(H - 1));
            int   yl = (int)floorf(yc);
            float ly = yc - (float)yl;
            wyl[iy] = ly * vy;
            wyh[iy] = (1.0f - ly) * vy;
            rowa[iy]  = yl * W;
            rstep[iy] = (yl < H - 1) ? W : 0;
        }
        int   colx[2];
        float wxh[2], wxl[2];
        #pragma unroll
        for (int ix = 0; ix < 2; ++ix) {
            float xf = fx0 + ((float)ix + 0.5f) * bin_w * 0.5f;
            float vx = (xf >= -1.0f && xf <= (float)W) ? 1.0f : 0.0f;
            float xc = fminf(fmaxf(xf, 0.0f), (float)(W - 1));
            int   xl = (int)floorf(xc);
            float lx = xc - (float)xl;   // == 0 exactly when xl == W-1
            wxl[ix] = lx * vx;
            wxh[ix] = (1.0f - lx) * vx;
            colx[ix] = xl;
        }

        // wait for THIS plane's 5 DMAs only; next plane's 5 stay in flight
        if (pre) asm volatile("s_waitcnt vmcnt(5)" ::: "memory");
        else     asm volatile("s_waitcnt vmcnt(0)" ::: "memory");
        __builtin_amdgcn_s_barrier();

        const float* pl = &plane[t & 1][0];
        float sum = 0.f;
        #pragma unroll
        for (int iy = 0; iy < 2; ++iy) {
            #pragma unroll
            for (int ix = 0; ix < 2; ++ix) {
                int a0 = rowa[iy] + colx[ix];
                int a1 = a0 + rstep[iy];
                float v11 = pl[a0];
                float v12 = pl[a0 + 1];
                float v21 = pl[a1];
                float v22 = pl[a1 + 1];
                float top = wxh[ix] * v11 + wxl[ix] * v12;
                float bot = wxh[ix] * v21 + wxl[ix] * v22;
                sum = fmaf(wyh[iy], top, sum);
                sum = fmaf(wyl[iy], bot, sum);
            }
        }
        out[(size_t)r * NCH + c] = sum * 0.25f;   // merges in XCD-local L2

        __builtin_amdgcn_s_barrier();   // all reads of buf done before reuse
    }
}

extern "C" void kernel_launch(void* const* d_in, const int* in_sizes, int n_in,
                              void* d_out, int out_size, void* d_ws, size_t ws_size,
                              hipStream_t stream) {
    const float* x     = (const float*)d_in[0];
    const float* boxes = (const float*)d_in[1];
    float* out = (float*)d_out;

    (void)in_sizes; (void)n_in; (void)out_size; (void)d_ws; (void)ws_size;

    hipLaunchKernelGGL(psroi_kernel, dim3(8 * JJ), dim3(512), 0, stream,
                       x, boxes, out);
}